// Round 2
// baseline (23595.583 us; speedup 1.0000x reference)
//
#include <hip/hip_runtime.h>
#include <hip/hip_bf16.h>

// LSTMOutputProj round 2: persistent kernel, 2 grid barriers/step.
//  X: cur(s-1) from logitbuf (block-local) + L0 MFMA -> h0(s)
//  Y: L1 MFMA (K=2048) -> h1(s) + fused partial-logit atomicAdds
// All cross-block data via agent-scope relaxed atomics (MALL-coherent, no L2 inv).
// Decomp: i=8 row-groups (64 rows) x j=32 col-groups (32 cols/gate), XCD-swizzled.

#define G4 4096
#define NOUTC 33
#define NSTEPS 128

typedef __attribute__((ext_vector_type(8))) short s8v;
typedef __attribute__((ext_vector_type(4))) float f4v;
typedef unsigned int u32;
typedef unsigned long long u64;

__device__ __forceinline__ float fsig(float x)  { return 1.0f / (1.0f + __expf(-x)); }
__device__ __forceinline__ float ftanh(float x) { return 2.0f / (1.0f + __expf(-2.0f * x)) - 1.0f; }

__device__ __forceinline__ short f2bf(float x) {
  union { __hip_bfloat16 b; short s; } u; u.b = __float2bfloat16(x); return u.s;
}
__device__ __forceinline__ float bf2f(short s) {
  union { __hip_bfloat16 b; short v; } u; u.v = s; return __bfloat162float(u.b);
}

// ---- coherent (agent-scope, L2-bypassing) accessors --------------------------
__device__ __forceinline__ u64 aload64(const void* p) {
  return __hip_atomic_load((const u64*)p, __ATOMIC_RELAXED, __HIP_MEMORY_SCOPE_AGENT);
}
__device__ __forceinline__ float aloadf(const float* p) {
  return __hip_atomic_load(p, __ATOMIC_RELAXED, __HIP_MEMORY_SCOPE_AGENT);
}
__device__ __forceinline__ void astore32(u32* p, u32 v) {
  __hip_atomic_store(p, v, __ATOMIC_RELAXED, __HIP_MEMORY_SCOPE_AGENT);
}
__device__ __forceinline__ void astoref(float* p, float v) {
  __hip_atomic_store(p, v, __ATOMIC_RELAXED, __HIP_MEMORY_SCOPE_AGENT);
}
__device__ __forceinline__ s8v aloadfrag(const short* p) {
  union { u64 u[2]; s8v v; } r;
  r.u[0] = aload64(p);
  r.u[1] = aload64(p + 4);
  return r.v;
}

// ---- grid barrier: no fences, no L2 inv. All exchanged data is sc1-coherent. -
__device__ __forceinline__ void gridbar(u32* bar, u32 target) {
  __builtin_amdgcn_s_waitcnt(0);  // drain this wave's outstanding sc1 stores
  __syncthreads();                // all waves drained (compiler waits vm before barrier)
  if (threadIdx.x == 0) {
    __hip_atomic_fetch_add(bar, 1u, __ATOMIC_RELAXED, __HIP_MEMORY_SCOPE_AGENT);
    while (__hip_atomic_load(bar, __ATOMIC_RELAXED, __HIP_MEMORY_SCOPE_AGENT) < target)
      __builtin_amdgcn_s_sleep(2);
  }
  __syncthreads();
}

// ---------------- precompute: transpose -> fragment-linearized bf16 -----------
__global__ __launch_bounds__(256) void transpose_frag_kernel(
    const float* __restrict__ src, short* __restrict__ dst_hi,
    short* __restrict__ dst_lo, int NK, int koff) {
  __shared__ float St[64][65];
  int n0 = (blockIdx.x & 63) * 64;
  int k0 = (blockIdx.x >> 6) * 64;
  int t = threadIdx.x;
  int nl = t & 63, kl = t >> 6;
#pragma unroll
  for (int it = 0; it < 16; ++it) {
    int k = kl + it * 4;
    St[k][nl] = src[(size_t)(k0 + k) * 4096 + n0 + nl];
  }
  __syncthreads();
  int lane = t & 63, w = t >> 6;
  for (int it = 0; it < 2; ++it) {
    int sub = it * 4 + w;
    int nt = sub >> 1, kc = sub & 1;
    int nloc = nt * 16 + (lane & 15);
    int kbase = kc * 32 + (lane >> 4) * 8;
    float v[8];
#pragma unroll
    for (int ii = 0; ii < 8; ++ii) v[ii] = St[kbase + ii][nloc];
    s8v hv;
#pragma unroll
    for (int ii = 0; ii < 8; ++ii) hv[ii] = f2bf(v[ii]);
    size_t ntg = (size_t)(n0 / 16 + nt);
    size_t kcg = (size_t)(k0 / 32 + kc + koff);
    size_t off = (ntg * (size_t)NK + kcg) * 512 + (size_t)lane * 8;
    *(s8v*)(dst_hi + off) = hv;
    if (dst_lo) {
      s8v lv;
#pragma unroll
      for (int ii = 0; ii < 8; ++ii) lv[ii] = f2bf(v[ii] - bf2f(hv[ii]));
      *(s8v*)(dst_lo + off) = lv;
    }
  }
}

// ---------------- precompute: cond = x @ Wc + bc  (split bf16 hi/lo) ----------
__global__ __launch_bounds__(256) void cond_kernel(
    const float* __restrict__ x, const float* __restrict__ Wc,
    const float* __restrict__ bc, short* __restrict__ cond_hi,
    short* __restrict__ cond_lo) {
  __shared__ float xs[8][512];
  int rb = (blockIdx.x >> 2) * 8;
  int cb = (blockIdx.x & 3) * 256;
  int t = threadIdx.x;
  for (int i = t; i < 8 * 512; i += 256)
    xs[i >> 9][i & 511] = x[(size_t)(rb + (i >> 9)) * 512 + (i & 511)];
  __syncthreads();
  float acc[8] = {0, 0, 0, 0, 0, 0, 0, 0};
  for (int k = 0; k < 512; ++k) {
    float w = Wc[(size_t)k * 1024 + cb + t];
#pragma unroll
    for (int rr = 0; rr < 8; ++rr) acc[rr] += xs[rr][k] * w;
  }
  float bcv = bc[cb + t];
#pragma unroll
  for (int rr = 0; rr < 8; ++rr) {
    float v = acc[rr] + bcv;
    short hi = f2bf(v);
    cond_hi[(size_t)(rb + rr) * 1024 + cb + t] = hi;
    cond_lo[(size_t)(rb + rr) * 1024 + cb + t] = f2bf(v - bf2f(hi));
  }
}

// ---------------- precompute: vec0, Wf, b1vec ---------------------------------
__global__ __launch_bounds__(256) void vecs_kernel(
    const float* __restrict__ Wih0, const float* __restrict__ bi,
    const float* __restrict__ Wi, const float* __restrict__ bih0,
    const float* __restrict__ bhh0, const float* __restrict__ bih1,
    const float* __restrict__ bhh1, float* __restrict__ vec0,
    float* __restrict__ Wf, float* __restrict__ b1vec) {
  int n = blockIdx.x * 256 + threadIdx.x;
  float v0 = 0.f, w0 = 0.f, w1 = 0.f;
  for (int k = 0; k < 1024; ++k) {
    float w = Wih0[(size_t)k * 4096 + n];
    v0 += bi[k] * w;
    w0 += Wi[k] * w;
    w1 += Wi[1024 + k] * w;
  }
  vec0[n] = v0 + bih0[n] + bhh0[n];
  Wf[2 * n + 0] = w0;
  Wf[2 * n + 1] = w1;
  b1vec[n] = bih1[n] + bhh1[n];
}

// ---------------- precompute: const0 = cond @ Wih0[H:] + vec0  (split bf16) ---
__global__ __launch_bounds__(512) void const0_kernel(
    const short* __restrict__ cond_hi, const short* __restrict__ cond_lo,
    const short* __restrict__ WTc_hi, const short* __restrict__ WTc_lo,
    const float* __restrict__ vec0, float* __restrict__ const0) {
  int j = blockIdx.x & 63, i = blockIdx.x >> 6;
  int w = threadIdx.x >> 6, lane = threadIdx.x & 63;
  int quad = lane >> 4, l16 = lane & 15;
  int rowA = i * 128 + w * 16 + l16;
  int rowC = i * 128 + w * 16 + quad * 4;
  int hid = j * 16 + l16;
  const short* ah = cond_hi + (size_t)rowA * 1024 + quad * 8;
  const short* al = cond_lo + (size_t)rowA * 1024 + quad * 8;
  f4v acc[4];
#pragma unroll
  for (int g = 0; g < 4; ++g) acc[g] = (f4v){0.f, 0.f, 0.f, 0.f};
#pragma unroll 2
  for (int kk = 0; kk < 32; ++kk) {
    s8v avh = *(const s8v*)(ah + kk * 32);
    s8v avl = *(const s8v*)(al + kk * 32);
#pragma unroll
    for (int g = 0; g < 4; ++g) {
      size_t off = ((size_t)(g * 64 + j) * 32 + kk) * 512 + (size_t)lane * 8;
      s8v bh = *(const s8v*)(WTc_hi + off);
      s8v bl = *(const s8v*)(WTc_lo + off);
      acc[g] = __builtin_amdgcn_mfma_f32_16x16x32_bf16(avh, bh, acc[g], 0, 0, 0);
      acc[g] = __builtin_amdgcn_mfma_f32_16x16x32_bf16(avh, bl, acc[g], 0, 0, 0);
      acc[g] = __builtin_amdgcn_mfma_f32_16x16x32_bf16(avl, bh, acc[g], 0, 0, 0);
    }
  }
#pragma unroll
  for (int g = 0; g < 4; ++g) {
    float vv = vec0[g * 1024 + hid];
#pragma unroll
    for (int p = 0; p < 4; ++p) {
      int r = rowC + p;
      const0[(size_t)r * G4 + g * 1024 + hid] = acc[g][p] + vv;
    }
  }
}

// ---------------- main persistent kernel --------------------------------------
__global__ __launch_bounds__(512, 2) void lstm_main(
    const short* __restrict__ WT0, const short* __restrict__ WT1,
    const float* __restrict__ const0, const float* __restrict__ Wf,
    const float* __restrict__ b1vec, const float* __restrict__ Wo,
    const float* __restrict__ bo, const float* __restrict__ sos,
    float* __restrict__ out, short* __restrict__ hbuf,
    float* __restrict__ logitbuf, u32* __restrict__ bar) {
  const int bid = blockIdx.x, tid = threadIdx.x;
  const int xcd = bid & 7, uu = (bid >> 3) & 3, i = bid >> 5;
  const int j = xcd * 4 + uu;                  // 0..31, 4 j-slices per XCD
  const int w = tid >> 6, lane = tid & 63;
  const int rt = w >> 1, ntg = w & 1;
  const int quad = lane >> 4, l16 = lane & 15, quad8 = quad * 8;
  const int rowA = i * 64 + rt * 16 + l16;
  const int rowC = i * 64 + rt * 16 + quad * 4;
  const int hid = j * 32 + ntg * 16 + l16;     // column within each gate's 1024
  __shared__ float curLDS[64][2];

  // zero hbuf (both banks): 4MB = 1M u32 via coherent stores
  {
    u32* hz = (u32*)hbuf;
    int base = bid * 512 + tid;
#pragma unroll
    for (int it = 0; it < 8; ++it) astore32(hz + base + it * 131072, 0u);
  }
  u32 snum = 1;
  gridbar(bar, snum * 256u);

  // step-invariant per-thread data
  float c0v[4][4], wfv[4][2], b1v[4], wov[NOUTC];
#pragma unroll
  for (int g = 0; g < 4; ++g) {
    wfv[g][0] = Wf[(g * 1024 + hid) * 2 + 0];
    wfv[g][1] = Wf[(g * 1024 + hid) * 2 + 1];
    b1v[g] = b1vec[g * 1024 + hid];
#pragma unroll
    for (int p = 0; p < 4; ++p)
      c0v[g][p] = const0[(size_t)(rowC + p) * G4 + g * 1024 + hid];
  }
#pragma unroll
  for (int ch = 0; ch < NOUTC; ++ch) wov[ch] = Wo[(size_t)hid * NOUTC + ch];

  const int rl = tid >> 3, sub = tid & 7;      // cur-compute mapping: 64 rows x 8 lanes
  float bov[5];
#pragma unroll
  for (int k = 0; k < 5; ++k) {
    int ch = sub + 8 * k;
    bov[k] = (ch < NOUTC) ? bo[ch] : 0.f;
  }
  size_t nb0[4], nb1[4];
#pragma unroll
  for (int g = 0; g < 4; ++g) {
    size_t nt = (size_t)(g * 64 + j * 2 + ntg);
    nb0[g] = nt * 32;
    nb1[g] = nt * 64;
  }
  float c0s[4] = {0.f, 0.f, 0.f, 0.f};
  float c1s[4] = {0.f, 0.f, 0.f, 0.f};

  for (int s = 0; s < NSTEPS; ++s) {
    const int bank_r = (s & 1) * 2048, bank_w = ((s + 1) & 1) * 2048;
    const int cb = s & 1, pb = cb ^ 1;

    // ---- X part 1: cur(s-1) local compute, out-write(s-1), zero logit bank cb
    if (s == 0) {
      if (sub == 0) { curLDS[rl][0] = sos[0]; curLDS[rl][1] = sos[1]; }
    } else {
      int r = i * 64 + rl;
      float lv[5];
#pragma unroll
      for (int k = 0; k < 5; ++k) {
        int ch = sub + 8 * k;
        lv[k] = (ch < NOUTC)
            ? aloadf(logitbuf + ((size_t)pb * 512 + r) * NOUTC + ch) + bov[k]
            : -1e30f;
      }
      if ((bid & 31) == 0) {  // j==0 blocks own the out-write for their rows
#pragma unroll
        for (int k = 0; k < 5; ++k) {
          int ch = sub + 8 * k;
          if (ch < NOUTC)
            out[((size_t)((r >> 6) * NOUTC + ch) * 64 + (r & 63)) * 128 + (s - 1)] = lv[k];
        }
      }
      float bv = -1e30f; int bi_ = 1 << 20;
#pragma unroll
      for (int k = 0; k < 5; ++k) {
        int ch = sub + 8 * k;
        if (ch >= 1 && ch < NOUTC && lv[k] > bv) { bv = lv[k]; bi_ = ch; }
      }
#pragma unroll
      for (int d = 1; d < 8; d <<= 1) {
        float ov = __shfl_xor(bv, d);
        int oi = __shfl_xor(bi_, d);
        if (ov > bv || (ov == bv && oi < bi_)) { bv = ov; bi_ = oi; }
      }
      if (sub == 0) {
        curLDS[rl][0] = (lv[0] > 0.0f) ? 1.0f : 0.0f;
        curLDS[rl][1] = (float)(bi_ - 1) * (1.0f / 31.0f);
      }
    }
    if ((bid & 31) == 0) {  // zero bank cb for Y(s)'s accumulation
      int r = i * 64 + rl;
#pragma unroll
      for (int k = 0; k < 5; ++k) {
        int ch = sub + 8 * k;
        if (ch < NOUTC) astoref(logitbuf + ((size_t)cb * 512 + r) * NOUTC + ch, 0.0f);
      }
    }
    __syncthreads();

    // ---- X part 2: L0 MFMA  g0 = h0(s-1)@Whh0 + const0 + cur@Wf -> h0(s)
    {
      f4v acc[4];
#pragma unroll
      for (int g = 0; g < 4; ++g) acc[g] = (f4v){0.f, 0.f, 0.f, 0.f};
      const short* ap = hbuf + (size_t)rowA * G4 + bank_r + quad8;
#pragma unroll 4
      for (int kk = 0; kk < 32; ++kk) {
        s8v av = aloadfrag(ap + kk * 32);
#pragma unroll
        for (int g = 0; g < 4; ++g) {
          s8v bv_ = *(const s8v*)(WT0 + (nb0[g] + kk) * 512 + (size_t)lane * 8);
          acc[g] = __builtin_amdgcn_mfma_f32_16x16x32_bf16(av, bv_, acc[g], 0, 0, 0);
        }
      }
#pragma unroll
      for (int p = 0; p < 4; ++p) {
        int r = rowC + p;
        int rr = r - i * 64;
        float cu0 = curLDS[rr][0], cu1 = curLDS[rr][1];
        float gi = acc[0][p] + c0v[0][p] + cu0 * wfv[0][0] + cu1 * wfv[0][1];
        float gf = acc[1][p] + c0v[1][p] + cu0 * wfv[1][0] + cu1 * wfv[1][1];
        float gg = acc[2][p] + c0v[2][p] + cu0 * wfv[2][0] + cu1 * wfv[2][1];
        float go = acc[3][p] + c0v[3][p] + cu0 * wfv[3][0] + cu1 * wfv[3][1];
        float cc = fsig(gf) * c0s[p] + fsig(gi) * ftanh(gg);
        c0s[p] = cc;
        float hf = fsig(go) * ftanh(cc);
        short hs = f2bf(hf);
        float hpart = __shfl_xor(hf, 1);
        if ((l16 & 1) == 0) {
          u32 val = (u32)(unsigned short)hs | ((u32)(unsigned short)f2bf(hpart) << 16);
          astore32((u32*)(hbuf + (size_t)r * G4 + bank_w + hid), val);
        }
      }
    }
    ++snum; gridbar(bar, snum * 256u);

    // ---- Y: L1 MFMA  g1 = h0(s)@Wih1 + h1(s-1)@Whh1 + b1 -> h1(s) + logits
    {
      f4v acc[4];
#pragma unroll
      for (int g = 0; g < 4; ++g) acc[g] = (f4v){0.f, 0.f, 0.f, 0.f};
      const short* ap0 = hbuf + (size_t)rowA * G4 + bank_w + quad8;         // h0(s)
      const short* ap1 = hbuf + (size_t)rowA * G4 + bank_r + 1024 + quad8;  // h1(s-1)
#pragma unroll 4
      for (int kk = 0; kk < 32; ++kk) {
        s8v av = aloadfrag(ap0 + kk * 32);
#pragma unroll
        for (int g = 0; g < 4; ++g) {
          s8v bv_ = *(const s8v*)(WT1 + (nb1[g] + kk) * 512 + (size_t)lane * 8);
          acc[g] = __builtin_amdgcn_mfma_f32_16x16x32_bf16(av, bv_, acc[g], 0, 0, 0);
        }
      }
#pragma unroll 4
      for (int kk = 0; kk < 32; ++kk) {
        s8v av = aloadfrag(ap1 + kk * 32);
#pragma unroll
        for (int g = 0; g < 4; ++g) {
          s8v bv_ = *(const s8v*)(WT1 + (nb1[g] + 32 + kk) * 512 + (size_t)lane * 8);
          acc[g] = __builtin_amdgcn_mfma_f32_16x16x32_bf16(av, bv_, acc[g], 0, 0, 0);
        }
      }
#pragma unroll
      for (int p = 0; p < 4; ++p) {
        int r = rowC + p;
        float gi = acc[0][p] + b1v[0];
        float gf = acc[1][p] + b1v[1];
        float gg = acc[2][p] + b1v[2];
        float go = acc[3][p] + b1v[3];
        float cc = fsig(gf) * c1s[p] + fsig(gi) * ftanh(gg);
        c1s[p] = cc;
        float hf = fsig(go) * ftanh(cc);
        short hs = f2bf(hf);
        float hq = bf2f(hs);  // bf16-rounded h1 (matches what next step reads)
        float hpart = __shfl_xor(hf, 1);
        if ((l16 & 1) == 0) {
          u32 val = (u32)(unsigned short)hs | ((u32)(unsigned short)f2bf(hpart) << 16);
          astore32((u32*)(hbuf + (size_t)r * G4 + bank_w + 1024 + hid), val);
        }
        // fused partial logits: sum over this quad's 16 hid values
        float* lrow = logitbuf + ((size_t)cb * 512 + r) * NOUTC;
#pragma unroll
        for (int ch = 0; ch < NOUTC; ++ch) {
          float sterm = hq * wov[ch];
          sterm += __shfl_xor(sterm, 1);
          sterm += __shfl_xor(sterm, 2);
          sterm += __shfl_xor(sterm, 4);
          sterm += __shfl_xor(sterm, 8);
          if (l16 == 0) atomicAdd(lrow + ch, sterm);
        }
      }
    }
    ++snum; gridbar(bar, snum * 256u);
  }

  // tail: write out logits for s=127 (accumulated in bank 1)
  if ((bid & 31) == 0) {
    int r = i * 64 + rl;
#pragma unroll
    for (int k = 0; k < 5; ++k) {
      int ch = sub + 8 * k;
      if (ch < NOUTC) {
        float lv = aloadf(logitbuf + ((size_t)1 * 512 + r) * NOUTC + ch) + bov[k];
        out[((size_t)((r >> 6) * NOUTC + ch) * 64 + (r & 63)) * 128 + 127] = lv;
      }
    }
  }
}

// ---------------- host launch -------------------------------------------------
extern "C" void kernel_launch(void* const* d_in, const int* in_sizes, int n_in,
                              void* d_out, int out_size, void* d_ws, size_t ws_size,
                              hipStream_t stream) {
  (void)in_sizes; (void)n_in; (void)out_size; (void)ws_size;
  const float* x    = (const float*)d_in[0];
  const float* sos  = (const float*)d_in[1];
  const float* Wc   = (const float*)d_in[2];
  const float* bc   = (const float*)d_in[3];
  const float* Wi   = (const float*)d_in[4];
  const float* bi   = (const float*)d_in[5];
  const float* Wih0 = (const float*)d_in[6];
  const float* Whh0 = (const float*)d_in[7];
  const float* bih0 = (const float*)d_in[8];
  const float* bhh0 = (const float*)d_in[9];
  const float* Wih1 = (const float*)d_in[10];
  const float* Whh1 = (const float*)d_in[11];
  const float* bih1 = (const float*)d_in[12];
  const float* bhh1 = (const float*)d_in[13];
  const float* Wo   = (const float*)d_in[14];
  const float* bo   = (const float*)d_in[15];
  float* out = (float*)d_out;

  char* p = (char*)d_ws;
  short* WT0     = (short*)p; p += (size_t)256 * 32 * 512 * 2;  // 8 MB
  short* WT1     = (short*)p; p += (size_t)256 * 64 * 512 * 2;  // 16 MB
  short* WTc_hi  = (short*)p; p += (size_t)256 * 32 * 512 * 2;  // 8 MB
  short* WTc_lo  = (short*)p; p += (size_t)256 * 32 * 512 * 2;  // 8 MB
  float* const0  = (float*)p; p += (size_t)512 * 4096 * 4;      // 8 MB
  short* hbuf    = (short*)p; p += (size_t)512 * 4096 * 2;      // 4 MB
  short* cond_hi = (short*)p; p += (size_t)512 * 1024 * 2;      // 1 MB
  short* cond_lo = (short*)p; p += (size_t)512 * 1024 * 2;      // 1 MB
  float* vec0    = (float*)p; p += 4096 * 4;
  float* Wf      = (float*)p; p += 4096 * 2 * 4;
  float* b1vec   = (float*)p; p += 4096 * 4;
  float* logitbuf= (float*)p; p += (size_t)2 * 512 * NOUTC * 4; // 135 KB
  u32*   bar     = (u32*)p;   p += 256;

  hipMemsetAsync(bar, 0, 256, stream);

  transpose_frag_kernel<<<1024, 256, 0, stream>>>(Whh0, WT0, nullptr, 32, 0);
  transpose_frag_kernel<<<1024, 256, 0, stream>>>(Wih1, WT1, nullptr, 64, 0);
  transpose_frag_kernel<<<1024, 256, 0, stream>>>(Whh1, WT1, nullptr, 64, 32);
  transpose_frag_kernel<<<1024, 256, 0, stream>>>(Wih0 + (size_t)1024 * 4096,
                                                  WTc_hi, WTc_lo, 32, 0);
  cond_kernel<<<256, 256, 0, stream>>>(x, Wc, bc, cond_hi, cond_lo);
  vecs_kernel<<<16, 256, 0, stream>>>(Wih0, bi, Wi, bih0, bhh0, bih1, bhh1,
                                      vec0, Wf, b1vec);
  const0_kernel<<<256, 512, 0, stream>>>(cond_hi, cond_lo, WTc_hi, WTc_lo,
                                         vec0, const0);
  lstm_main<<<256, 512, 0, stream>>>(WT0, WT1, const0, Wf, b1vec, Wo, bo, sos,
                                     out, hbuf, logitbuf, bar);
}